// Round 5
// baseline (681.965 us; speedup 1.0000x reference)
//
#include <hip/hip_runtime.h>
#include <hip/hip_bf16.h>

#define NB 4
#define NH 12
#define NS 2048
#define PD 64

typedef float f32x4 __attribute__((ext_vector_type(4)));
typedef short s16x8 __attribute__((ext_vector_type(8)));

#define MFMA(a, b, c) __builtin_amdgcn_mfma_f32_16x16x32_bf16((a), (b), (c), 0, 0, 0)

static __device__ __forceinline__ unsigned short bfbits(float x) {
    __hip_bfloat16 h = __float2bfloat16(x);            // RNE
    union { __hip_bfloat16 b; unsigned short u; } c; c.b = h; return c.u;
}
static __device__ __forceinline__ float bf2f(unsigned short u) {
    union { unsigned int i; float f; } c; c.i = ((unsigned int)u) << 16; return c.f;
}
static __device__ __forceinline__ float dot4(const float4& a) {
    return fmaf(a.x, a.x, fmaf(a.y, a.y, fmaf(a.z, a.z, a.w * a.w)));
}
// split float4 into bf16 hi (h4) and lo (l4), packed ushort4-in-uint2
static __device__ __forceinline__ void split4(float4 v, uint2& h4, uint2& l4) {
    unsigned short h0 = bfbits(v.x), h1 = bfbits(v.y), h2 = bfbits(v.z), h3 = bfbits(v.w);
    unsigned short l0 = bfbits(v.x - bf2f(h0)), l1 = bfbits(v.y - bf2f(h1));
    unsigned short l2 = bfbits(v.z - bf2f(h2)), l3 = bfbits(v.w - bf2f(h3));
    h4.x = (unsigned)h0 | ((unsigned)h1 << 16); h4.y = (unsigned)h2 | ((unsigned)h3 << 16);
    l4.x = (unsigned)l0 | ((unsigned)l1 << 16); l4.y = (unsigned)l2 | ((unsigned)l3 << 16);
}
static __device__ __forceinline__ uint2 cvt4h(float4 v) {
    uint2 h4;
    h4.x = (unsigned)bfbits(v.x) | ((unsigned)bfbits(v.y) << 16);
    h4.y = (unsigned)bfbits(v.z) | ((unsigned)bfbits(v.w) << 16);
    return h4;
}

__global__ __launch_bounds__(256, 3) void kde_attn_mfma(
    const float* __restrict__ Qg, const float* __restrict__ Kg,
    const float* __restrict__ Vg, const float* __restrict__ maskg,
    float* __restrict__ Xg)
{
    // LDS: sKh/sKl persistent; sU = {Q hi|lo during prologue} -> {P | Vt} in loop
    __shared__ __align__(16) unsigned short sKh[4096], sKl[4096];
    __shared__ __align__(16) unsigned short sU[8192];
    __shared__ float sdQ[64], scb[64], red[4];

    unsigned short* const sQh = sU;          // prologue
    unsigned short* const sQl = sU + 4096;   // prologue
    unsigned short* const sPh = sU;          // loop
    unsigned short* const sVth = sU + 4096;  // loop

    const int t    = threadIdx.x;
    const int lane = t & 63;
    const int w    = t >> 6;      // wave 0..3
    const int lq   = lane & 15;
    const int lk   = lane >> 4;
    const int wr2  = w >> 1;      // PV q-half
    const int wc2  = w & 1;       // PV p-half

    // XCD-bijective remap: 1536 blocks = 8 XCD * (6 bh * 32 qb)
    const int s   = blockIdx.x;
    const int xcd = s & 7;
    const int ii  = s >> 3;
    const int bh  = 6 * xcd + (ii >> 5);
    const int n0  = (ii & 31) * 64;
    const int b   = bh / NH;

    const float DN = 0.42044820762685725f;   // 32^(-0.25)

    const float* Qh = Qg + (size_t)bh * NS * PD;
    const float* Kh = Kg + (size_t)bh * NS * PD;
    const float* Vh = Vg + (size_t)bh * NS * PD;
    const float* mk = maskg + (size_t)b * NS;

    // ---- npn ----
    {
        float sm = 0.f;
        for (int i = t; i < NS; i += 256) sm += mk[i];
        #pragma unroll
        for (int m = 1; m < 64; m <<= 1) sm += __shfl_xor(sm, m);
        if (lane == 0) red[w] = sm;
    }

    // ---- stage Q (scaled, split, swizzled) + diag_Q ----
    #pragma unroll
    for (int j = 0; j < 4; ++j) {
        const int idx = j * 256 + t;
        const int row = idx >> 4;
        const int u   = idx & 15;
        const float qs = mk[n0 + row] * DN;
        float4 v = *(const float4*)(Qh + (size_t)(n0 + row) * PD + 4 * u);
        v.x *= qs; v.y *= qs; v.z *= qs; v.w *= qs;
        uint2 h4, l4; split4(v, h4, l4);
        const int iu = (row * 64 + 4 * u) ^ ((row & 7) << 3);
        *(uint2*)&sQh[iu] = h4;
        *(uint2*)&sQl[iu] = l4;
        float d = dot4(v);
        d += __shfl_xor(d, 1); d += __shfl_xor(d, 2);
        d += __shfl_xor(d, 4); d += __shfl_xor(d, 8);
        if (u == 0) sdQ[row] = 0.5f * d;
    }
    __syncthreads();

    const float npn  = red[0] + red[1] + red[2] + red[3];
    const float vscl = DN / npn;

    // ---- hoist Q fragments + dq to registers (frees sU) ----
    s16x8 aqh[4][2], aql[4][2];
    #pragma unroll
    for (int i2 = 0; i2 < 4; ++i2) {
        #pragma unroll
        for (int ks = 0; ks < 2; ++ks) {
            const int qrow = 16 * i2 + lq;
            const int io = (qrow * 64 + 32 * ks + 8 * lk) ^ ((lq & 7) << 3);
            aqh[i2][ks] = *(const s16x8*)&sQh[io];
            aql[i2][ks] = *(const s16x8*)&sQl[io];
        }
    }
    float dqv[4][4];
    #pragma unroll
    for (int i2 = 0; i2 < 4; ++i2)
        #pragma unroll
        for (int r = 0; r < 4; ++r)
            dqv[i2][r] = sdQ[16 * i2 + 4 * lk + r];
    __syncthreads();   // sU now free for P / Vt

    f32x4 xacc[2][2];
    #pragma unroll
    for (int i2 = 0; i2 < 2; ++i2)
        #pragma unroll
        for (int j2 = 0; j2 < 2; ++j2)
            xacc[i2][j2] = (f32x4){0.f, 0.f, 0.f, 0.f};

    for (int mt = 0; mt < NS / 64; ++mt) {
        const int m0 = mt * 64;

        // ---- stage K (scaled, split, swizzled) + column bias ----
        #pragma unroll
        for (int j = 0; j < 4; ++j) {
            const int idx = j * 256 + t;
            const int row = idx >> 4;
            const int u   = idx & 15;
            const float mr  = mk[m0 + row];
            const float ksc = mr * DN;
            float4 v = *(const float4*)(Kh + (size_t)(m0 + row) * PD + 4 * u);
            v.x *= ksc; v.y *= ksc; v.z *= ksc; v.w *= ksc;
            uint2 h4, l4; split4(v, h4, l4);
            const int iu = (row * 64 + 4 * u) ^ ((row & 7) << 3);
            *(uint2*)&sKh[iu] = h4;
            *(uint2*)&sKl[iu] = l4;
            float d = dot4(v);
            d += __shfl_xor(d, 1); d += __shfl_xor(d, 2);
            d += __shfl_xor(d, 4); d += __shfl_xor(d, 8);
            if (u == 0) scb[row] = fmaf(-1.0e9f, 1.f - mr, -0.5f * d);
        }
        // ---- stage V transposed (scaled, bf16 hi only, swizzled) ----
        #pragma unroll
        for (int j = 0; j < 4; ++j) {
            const int idx = j * 256 + t;
            const int p   = idx & 63;
            const int mq  = idx >> 6;      // wave-constant
            const float* vc = Vh + (size_t)(m0 + 4 * mq) * PD + p;
            float4 mr = *(const float4*)&mk[m0 + 4 * mq];
            float4 v = make_float4(vc[0] * (mr.x * vscl), vc[PD] * (mr.y * vscl),
                                   vc[2 * PD] * (mr.z * vscl), vc[3 * PD] * (mr.w * vscl));
            const int xv = ((p & 7) << 3) | (((p >> 4) & 3) << 2);
            *(uint2*)&sVth[(p * 64 + 4 * mq) ^ xv] = cvt4h(v);
        }
        __syncthreads();   // K, V, scb ready

        const float cbv = scb[16 * w + lq];

        // ---- S = Qs.Ks^T : wave w owns m-cols [16w,16w+16), all 64 q ----
        f32x4 acc[4];
        #pragma unroll
        for (int i2 = 0; i2 < 4; ++i2) acc[i2] = (f32x4){0.f, 0.f, 0.f, 0.f};

        #pragma unroll
        for (int ks = 0; ks < 2; ++ks) {
            const int mrow = 16 * w + lq;
            const int io = (mrow * 64 + 32 * ks + 8 * lk) ^ ((lq & 7) << 3);
            const s16x8 kh  = *(const s16x8*)&sKh[io];
            const s16x8 klo = *(const s16x8*)&sKl[io];
            #pragma unroll
            for (int i2 = 0; i2 < 4; ++i2) {
                acc[i2] = MFMA(aqh[i2][ks], kh,  acc[i2]);
                acc[i2] = MFMA(aqh[i2][ks], klo, acc[i2]);
                acc[i2] = MFMA(aql[i2][ks], kh,  acc[i2]);
            }
        }

        // ---- P = exp(S - dq + cb) -> bf16 into swizzled sP ----
        #pragma unroll
        for (int i2 = 0; i2 < 4; ++i2) {
            #pragma unroll
            for (int r = 0; r < 4; ++r) {
                const int q = 16 * i2 + 4 * lk + r;
                const float Pv = __expf(acc[i2][r] - dqv[i2][r] + cbv);
                sPh[(q * 64 + 16 * w + lq) ^ ((q & 7) << 3)] = bfbits(Pv);
            }
        }
        __syncthreads();   // P ready

        // ---- X += P . Vs (bf16), wave = (q-half wr2, p-half wc2) ----
        #pragma unroll
        for (int ks2 = 0; ks2 < 2; ++ks2) {
            s16x8 ph[2], vh[2];
            #pragma unroll
            for (int i2 = 0; i2 < 2; ++i2) {
                const int qr = 32 * wr2 + 16 * i2 + lq;
                ph[i2] = *(const s16x8*)&sPh[(qr * 64 + 32 * ks2 + 8 * lk) ^ ((lq & 7) << 3)];
            }
            #pragma unroll
            for (int j2 = 0; j2 < 2; ++j2) {
                const int pr = 32 * wc2 + 16 * j2 + lq;
                const int xv = ((pr & 7) << 3) | (((pr >> 4) & 3) << 2);
                const int base = pr * 64 + 32 * ks2 + 8 * lk;
                const uint2 a  = *(const uint2*)&sVth[(base) ^ xv];
                const uint2 bq = *(const uint2*)&sVth[(base + 4) ^ xv];
                union { uint4 u; s16x8 v; } cc;
                cc.u = make_uint4(a.x, a.y, bq.x, bq.y);
                vh[j2] = cc.v;
            }
            #pragma unroll
            for (int i2 = 0; i2 < 2; ++i2)
                #pragma unroll
                for (int j2 = 0; j2 < 2; ++j2)
                    xacc[i2][j2] = MFMA(ph[i2], vh[j2], xacc[i2][j2]);
        }
        __syncthreads();   // done with sP/sVt before next staging
    }

    // ---- write X ----
    float* Xh = Xg + (size_t)bh * NS * PD;
    #pragma unroll
    for (int i2 = 0; i2 < 2; ++i2)
        #pragma unroll
        for (int j2 = 0; j2 < 2; ++j2)
            #pragma unroll
            for (int r = 0; r < 4; ++r)
                Xh[(size_t)(n0 + 32 * wr2 + 16 * i2 + 4 * lk + r) * PD + 32 * wc2 + 16 * j2 + lq] =
                    xacc[i2][j2][r];
}

extern "C" void kernel_launch(void* const* d_in, const int* in_sizes, int n_in,
                              void* d_out, int out_size, void* d_ws, size_t ws_size,
                              hipStream_t stream) {
    const float* Q    = (const float*)d_in[0];
    const float* K    = (const float*)d_in[1];
    const float* V    = (const float*)d_in[2];
    const float* mask = (const float*)d_in[3];
    float* X = (float*)d_out;

    kde_attn_mfma<<<dim3(NB * NH * (NS / 64)), dim3(256), 0, stream>>>(Q, K, V, mask, X);
}

// Round 6
// 233.716 us; speedup vs baseline: 2.9179x; 2.9179x over previous
//
#include <hip/hip_runtime.h>
#include <hip/hip_bf16.h>

#define NB 4
#define NH 12
#define NS 2048
#define PD 64

typedef float f32x4  __attribute__((ext_vector_type(4)));
typedef float f32x16 __attribute__((ext_vector_type(16)));
typedef short s16x8  __attribute__((ext_vector_type(8)));
typedef unsigned int u32x2 __attribute__((ext_vector_type(2)));

#define MFMA32(a, b, c) __builtin_amdgcn_mfma_f32_32x32x16_bf16((a), (b), (c), 0, 0, 0)

static __device__ __forceinline__ unsigned short bfbits(float x) {
    __hip_bfloat16 h = __float2bfloat16(x);            // RNE
    union { __hip_bfloat16 b; unsigned short u; } c; c.b = h; return c.u;
}
static __device__ __forceinline__ float bf2f(unsigned short u) {
    union { unsigned int i; float f; } c; c.i = ((unsigned int)u) << 16; return c.f;
}
static __device__ __forceinline__ float dot4(const float4& a) {
    return fmaf(a.x, a.x, fmaf(a.y, a.y, fmaf(a.z, a.z, a.w * a.w)));
}
static __device__ __forceinline__ void split4(float4 v, uint2& h4, uint2& l4) {
    unsigned short h0 = bfbits(v.x), h1 = bfbits(v.y), h2 = bfbits(v.z), h3 = bfbits(v.w);
    unsigned short l0 = bfbits(v.x - bf2f(h0)), l1 = bfbits(v.y - bf2f(h1));
    unsigned short l2 = bfbits(v.z - bf2f(h2)), l3 = bfbits(v.w - bf2f(h3));
    h4.x = (unsigned)h0 | ((unsigned)h1 << 16); h4.y = (unsigned)h2 | ((unsigned)h3 << 16);
    l4.x = (unsigned)l0 | ((unsigned)l1 << 16); l4.y = (unsigned)l2 | ((unsigned)l3 << 16);
}
static __device__ __forceinline__ uint2 cvt4h(float4 v) {
    uint2 h4;
    h4.x = (unsigned)bfbits(v.x) | ((unsigned)bfbits(v.y) << 16);
    h4.y = (unsigned)bfbits(v.z) | ((unsigned)bfbits(v.w) << 16);
    return h4;
}
static __device__ __forceinline__ unsigned int pk2(float a, float b) {
    return (unsigned)bfbits(a) | ((unsigned)bfbits(b) << 16);
}
// swizzled b128 fragment load: row-major [64]-stride tile, XOR bank swizzle
static __device__ __forceinline__ s16x8 ldfrag(const unsigned short* s, int row, int kc) {
    return *(const s16x8*)&s[(row * 64 + kc) ^ ((row & 7) << 3)];
}
// permlane32_swap: a' = {a[0:31], b[0:31]}, b' = {a[32:63], b[32:63]}
static __device__ __forceinline__ void pswap(unsigned int& a, unsigned int& b) {
#if __has_builtin(__builtin_amdgcn_permlane32_swap)
    u32x2 r = __builtin_amdgcn_permlane32_swap(a, b, false, false);
    a = r[0]; b = r[1];
#else
    const unsigned ax = (unsigned)__shfl_xor((int)a, 32);
    const unsigned bx = (unsigned)__shfl_xor((int)b, 32);
    const bool hi = (threadIdx.x & 32) != 0;
    const unsigned na = hi ? bx : a;
    const unsigned nb = hi ? b : ax;
    a = na; b = nb;
#endif
}

__global__ __launch_bounds__(256, 2) void kde_attn_mfma(
    const float* __restrict__ Qg, const float* __restrict__ Kg,
    const float* __restrict__ Vg, const float* __restrict__ maskg,
    float* __restrict__ Xg)
{
    __shared__ __align__(16) unsigned short sKh[4096], sKl[4096], sVt[4096];
    __shared__ __align__(16) unsigned short sU[8192];   // {Q hi|lo} prologue -> sX epilogue
    __shared__ __align__(16) float scb[64];
    __shared__ float sdQ[64], red[4];

    unsigned short* const sQh = sU;
    unsigned short* const sQl = sU + 4096;

    const int t    = threadIdx.x;
    const int lane = t & 63;
    const int w    = t >> 6;
    const int h    = lane >> 5;    // lane half
    const int c    = lane & 31;    // col within 32
    const int wm   = w >> 1;       // m-half this wave owns
    const int wq   = w & 1;        // q-half this wave owns

    // XCD-bijective remap: 1536 blocks = 8 XCD * (6 bh * 32 qb)
    const int s   = blockIdx.x;
    const int xcd = s & 7;
    const int ii  = s >> 3;
    const int bh  = 6 * xcd + (ii >> 5);
    const int n0  = (ii & 31) * 64;
    const int b   = bh / NH;

    const float DN = 0.42044820762685725f;   // 32^(-0.25)

    const float* Qh = Qg + (size_t)bh * NS * PD;
    const float* Kh = Kg + (size_t)bh * NS * PD;
    const float* Vh = Vg + (size_t)bh * NS * PD;
    const float* mk = maskg + (size_t)b * NS;

    // ---- npn ----
    {
        float sm = 0.f;
        for (int i = t; i < NS; i += 256) sm += mk[i];
        #pragma unroll
        for (int m = 1; m < 64; m <<= 1) sm += __shfl_xor(sm, m);
        if (lane == 0) red[w] = sm;
    }

    // ---- stage Q (scaled, split, swizzled) + diag_Q ----
    #pragma unroll
    for (int j = 0; j < 4; ++j) {
        const int idx = j * 256 + t;
        const int row = idx >> 4;
        const int u   = idx & 15;
        const float qs = mk[n0 + row] * DN;
        float4 v = *(const float4*)(Qh + (size_t)(n0 + row) * PD + 4 * u);
        v.x *= qs; v.y *= qs; v.z *= qs; v.w *= qs;
        uint2 h4, l4; split4(v, h4, l4);
        const int iu = (row * 64 + 4 * u) ^ ((row & 7) << 3);
        *(uint2*)&sQh[iu] = h4;
        *(uint2*)&sQl[iu] = l4;
        float d = dot4(v);
        d += __shfl_xor(d, 1); d += __shfl_xor(d, 2);
        d += __shfl_xor(d, 4); d += __shfl_xor(d, 8);
        if (u == 0) sdQ[row] = 0.5f * d;
    }
    __syncthreads();

    const float npn  = red[0] + red[1] + red[2] + red[3];
    const float vscl = DN / npn;

    // ---- hoist Q B-fragments (8 x b128 = 32 VGPR) + per-lane dq ----
    s16x8 qbh[4], qbl[4];
    #pragma unroll
    for (int ks = 0; ks < 4; ++ks) {
        const int kc = 16 * ks + 8 * h;
        qbh[ks] = ldfrag(sQh, 32 * wq + c, kc);
        qbl[ks] = ldfrag(sQl, 32 * wq + c, kc);
    }
    const float dq = sdQ[32 * wq + c];

    f32x16 xacc[2];
    #pragma unroll
    for (int pt = 0; pt < 2; ++pt)
        #pragma unroll
        for (int r = 0; r < 16; ++r) xacc[pt][r] = 0.f;

    for (int mt = 0; mt < NS / 64; ++mt) {
        const int m0 = mt * 64;

        // ---- stage K (scaled, split, swizzled) + column bias ----
        #pragma unroll
        for (int j = 0; j < 4; ++j) {
            const int idx = j * 256 + t;
            const int row = idx >> 4;
            const int u   = idx & 15;
            const float mr  = mk[m0 + row];
            const float ksc = mr * DN;
            float4 v = *(const float4*)(Kh + (size_t)(m0 + row) * PD + 4 * u);
            v.x *= ksc; v.y *= ksc; v.z *= ksc; v.w *= ksc;
            uint2 h4, l4; split4(v, h4, l4);
            const int iu = (row * 64 + 4 * u) ^ ((row & 7) << 3);
            *(uint2*)&sKh[iu] = h4;
            *(uint2*)&sKl[iu] = l4;
            float d = dot4(v);
            d += __shfl_xor(d, 1); d += __shfl_xor(d, 2);
            d += __shfl_xor(d, 4); d += __shfl_xor(d, 8);
            if (u == 0) scb[row] = fmaf(-1.0e9f, 1.f - mr, -0.5f * d);
        }
        // ---- stage V^T (scaled, bf16-hi, swizzled [p][m]) ----
        #pragma unroll
        for (int j = 0; j < 4; ++j) {
            const int p  = lane;
            const int mq = 4 * j + ((w + (p >> 3)) & 3);   // de-conflicts write banks
            const float* vc = Vh + (size_t)(m0 + 4 * mq) * PD + p;
            float4 mr = *(const float4*)&mk[m0 + 4 * mq];
            float4 v = make_float4(vc[0] * (mr.x * vscl), vc[PD] * (mr.y * vscl),
                                   vc[2 * PD] * (mr.z * vscl), vc[3 * PD] * (mr.w * vscl));
            *(uint2*)&sVt[(p * 64 + 4 * mq) ^ ((p & 7) << 3)] = cvt4h(v);
        }
        __syncthreads();

        // ---- S^T = Ks . Qs^T : rows=m (wave's 32), cols=q (wave's 32) ----
        f32x16 acc;
        #pragma unroll
        for (int r = 0; r < 16; ++r) acc[r] = 0.f;

        __builtin_amdgcn_s_setprio(1);
        #pragma unroll
        for (int ks = 0; ks < 4; ++ks) {
            const int kc = 16 * ks + 8 * h;
            const s16x8 kh = ldfrag(sKh, 32 * wm + c, kc);
            const s16x8 kl = ldfrag(sKl, 32 * wm + c, kc);
            acc = MFMA32(kh, qbh[ks], acc);
            acc = MFMA32(kh, qbl[ks], acc);
            acc = MFMA32(kl, qbh[ks], acc);
        }
        __builtin_amdgcn_s_setprio(0);

        // ---- P = exp(S - dq + cb) in-register ----
        float pv[16];
        #pragma unroll
        for (int g = 0; g < 4; ++g) {
            const f32x4 cb4 = *(const f32x4*)&scb[32 * wm + 8 * g + 4 * h];
            #pragma unroll
            for (int e = 0; e < 4; ++e)
                pv[4 * g + e] = __expf(acc[4 * g + e] - dq + cb4[e]);
        }

        // ---- X_partial += P^T . Vs : pack + permlane32_swap -> A-frag ----
        #pragma unroll
        for (int ks2 = 0; ks2 < 2; ++ks2) {
            const int bb = 8 * ks2;
            unsigned w0 = pk2(pv[bb + 0], pv[bb + 1]);
            unsigned w1 = pk2(pv[bb + 2], pv[bb + 3]);
            unsigned w2 = pk2(pv[bb + 4], pv[bb + 5]);
            unsigned w3 = pk2(pv[bb + 6], pv[bb + 7]);
            pswap(w0, w2);
            pswap(w1, w3);
            union { unsigned int u[4]; s16x8 v; } pa;
            pa.u[0] = w0; pa.u[1] = w1; pa.u[2] = w2; pa.u[3] = w3;
            const int kc = 32 * wm + 16 * ks2 + 8 * h;
            __builtin_amdgcn_s_setprio(1);
            #pragma unroll
            for (int pt = 0; pt < 2; ++pt) {
                const s16x8 vb = ldfrag(sVt, 32 * pt + c, kc);
                xacc[pt] = MFMA32(pa.v, vb, xacc[pt]);
            }
            __builtin_amdgcn_s_setprio(0);
        }
        __syncthreads();   // protect sK/sVt before next staging
    }

    // ---- cross-wave (wm) reduction via LDS, then write X ----
    float* sX = (float*)sU;
    if (wm == 0) {
        #pragma unroll
        for (int pt = 0; pt < 2; ++pt)
            #pragma unroll
            for (int r = 0; r < 16; ++r) {
                const int row = 32 * wq + (r & 3) + 8 * (r >> 2) + 4 * h;
                sX[row * 64 + 32 * pt + c] = xacc[pt][r];
            }
    }
    __syncthreads();
    if (wm == 1) {
        float* Xh = Xg + (size_t)bh * NS * PD;
        #pragma unroll
        for (int pt = 0; pt < 2; ++pt)
            #pragma unroll
            for (int r = 0; r < 16; ++r) {
                const int row = 32 * wq + (r & 3) + 8 * (r >> 2) + 4 * h;
                const int col = 32 * pt + c;
                Xh[(size_t)(n0 + row) * PD + col] = sX[row * 64 + col] + xacc[pt][r];
            }
    }
}

extern "C" void kernel_launch(void* const* d_in, const int* in_sizes, int n_in,
                              void* d_out, int out_size, void* d_ws, size_t ws_size,
                              hipStream_t stream) {
    const float* Q    = (const float*)d_in[0];
    const float* K    = (const float*)d_in[1];
    const float* V    = (const float*)d_in[2];
    const float* mask = (const float*)d_in[3];
    float* X = (float*)d_out;

    kde_attn_mfma<<<dim3(NB * NH * (NS / 64)), dim3(256), 0, stream>>>(Q, K, V, mask, X);
}

// Round 7
// 136.091 us; speedup vs baseline: 5.0111x; 1.7173x over previous
//
#include <hip/hip_runtime.h>
#include <hip/hip_bf16.h>

#define NB 4
#define NH 12
#define NS 2048
#define PD 64
#define CHUNK 25600   // 3*8192 (Khi,Klo,Vt bf16 swizzled) + 1024 (cb x4 replicas)

typedef float f32x4  __attribute__((ext_vector_type(4)));
typedef float f32x16 __attribute__((ext_vector_type(16)));
typedef short s16x8  __attribute__((ext_vector_type(8)));
typedef unsigned int u32x2 __attribute__((ext_vector_type(2)));

#define MFMA32(a, b, c) __builtin_amdgcn_mfma_f32_32x32x16_bf16((a), (b), (c), 0, 0, 0)

typedef const __attribute__((address_space(1))) unsigned int* gas_t;
typedef __attribute__((address_space(3))) unsigned int* las_t;

static __device__ __forceinline__ unsigned short bfbits(float x) {
    __hip_bfloat16 h = __float2bfloat16(x);            // RNE
    union { __hip_bfloat16 b; unsigned short u; } c; c.b = h; return c.u;
}
static __device__ __forceinline__ float bf2f(unsigned short u) {
    union { unsigned int i; float f; } c; c.i = ((unsigned int)u) << 16; return c.f;
}
static __device__ __forceinline__ float dot4(const float4& a) {
    return fmaf(a.x, a.x, fmaf(a.y, a.y, fmaf(a.z, a.z, a.w * a.w)));
}
static __device__ __forceinline__ void split4(float4 v, uint2& h4, uint2& l4) {
    unsigned short h0 = bfbits(v.x), h1 = bfbits(v.y), h2 = bfbits(v.z), h3 = bfbits(v.w);
    unsigned short l0 = bfbits(v.x - bf2f(h0)), l1 = bfbits(v.y - bf2f(h1));
    unsigned short l2 = bfbits(v.z - bf2f(h2)), l3 = bfbits(v.w - bf2f(h3));
    h4.x = (unsigned)h0 | ((unsigned)h1 << 16); h4.y = (unsigned)h2 | ((unsigned)h3 << 16);
    l4.x = (unsigned)l0 | ((unsigned)l1 << 16); l4.y = (unsigned)l2 | ((unsigned)l3 << 16);
}
static __device__ __forceinline__ uint2 cvt4h(float4 v) {
    uint2 h4;
    h4.x = (unsigned)bfbits(v.x) | ((unsigned)bfbits(v.y) << 16);
    h4.y = (unsigned)bfbits(v.z) | ((unsigned)bfbits(v.w) << 16);
    return h4;
}
static __device__ __forceinline__ unsigned int pk2(float a, float b) {
    return (unsigned)bfbits(a) | ((unsigned)bfbits(b) << 16);
}
static __device__ __forceinline__ s16x8 ldfrag(const unsigned short* s, int row, int kc) {
    return *(const s16x8*)&s[(row * 64 + kc) ^ ((row & 7) << 3)];
}
static __device__ __forceinline__ void pswap(unsigned int& a, unsigned int& b) {
#if __has_builtin(__builtin_amdgcn_permlane32_swap)
    u32x2 r = __builtin_amdgcn_permlane32_swap(a, b, false, false);
    a = r[0]; b = r[1];
#else
    const unsigned ax = (unsigned)__shfl_xor((int)a, 32);
    const unsigned bx = (unsigned)__shfl_xor((int)b, 32);
    const bool hi = (threadIdx.x & 32) != 0;
    const unsigned na = hi ? bx : a;
    const unsigned nb = hi ? b : ax;
    a = na; b = nb;
#endif
}
// stage 1KB: 64 lanes x 16B. g already includes +16*lane; l is wave-uniform base.
static __device__ __forceinline__ void gld16(const void* g, void* l) {
#if __has_builtin(__builtin_amdgcn_global_load_lds)
    __builtin_amdgcn_global_load_lds((gas_t)g, (las_t)l, 16, 0, 0);
#else
    ((uint4*)l)[threadIdx.x & 63] = *(const uint4*)g;
#endif
}

// ---------------- precompute: build swizzled K/V/cb chunks in ws ----------------
__global__ __launch_bounds__(256, 4) void kde_pre(
    const float* __restrict__ Kg, const float* __restrict__ Vg,
    const float* __restrict__ maskg, unsigned char* __restrict__ ws)
{
    __shared__ float red[4];

    const int t    = threadIdx.x;
    const int lane = t & 63;
    const int w    = t >> 6;

    const int s   = blockIdx.x;
    const int xcd = s & 7;
    const int ii  = s >> 3;
    const int bh  = 6 * xcd + (ii >> 5);
    const int mt  = ii & 31;
    const int b   = bh / NH;
    const int m0  = mt * 64;

    const float DN = 0.42044820762685725f;

    const float* Kh = Kg + (size_t)bh * NS * PD;
    const float* Vh = Vg + (size_t)bh * NS * PD;
    const float* mk = maskg + (size_t)b * NS;

    float sm = 0.f;
    for (int i = t; i < NS; i += 256) sm += mk[i];
    #pragma unroll
    for (int m = 1; m < 64; m <<= 1) sm += __shfl_xor(sm, m);
    if (lane == 0) red[w] = sm;
    __syncthreads();
    const float npn  = red[0] + red[1] + red[2] + red[3];
    const float vscl = DN / npn;

    unsigned char* ch = ws + (size_t)(bh * 32 + mt) * CHUNK;
    unsigned short* gKh = (unsigned short*)ch;
    unsigned short* gKl = gKh + 4096;
    unsigned short* gVt = gKh + 8192;
    float* gcb = (float*)(ch + 24576);

    // K tile: scale, split, swizzled store + column bias (4 replicas)
    #pragma unroll
    for (int j = 0; j < 4; ++j) {
        const int idx = j * 256 + t;
        const int row = idx >> 4;
        const int u   = idx & 15;
        const float mr  = mk[m0 + row];
        const float ksc = mr * DN;
        float4 v = *(const float4*)(Kh + (size_t)(m0 + row) * PD + 4 * u);
        v.x *= ksc; v.y *= ksc; v.z *= ksc; v.w *= ksc;
        uint2 h4, l4; split4(v, h4, l4);
        const int iu = (row * 64 + 4 * u) ^ ((row & 7) << 3);
        *(uint2*)&gKh[iu] = h4;
        *(uint2*)&gKl[iu] = l4;
        float d = dot4(v);
        d += __shfl_xor(d, 1); d += __shfl_xor(d, 2);
        d += __shfl_xor(d, 4); d += __shfl_xor(d, 8);
        if (u == 0) {
            const float cb = fmaf(-1.0e9f, 1.f - mr, -0.5f * d);
            gcb[row] = cb; gcb[64 + row] = cb; gcb[128 + row] = cb; gcb[192 + row] = cb;
        }
    }
    // V^T tile: scale, bf16-hi, swizzled store
    #pragma unroll
    for (int j = 0; j < 4; ++j) {
        const int p  = lane;
        const int mq = 4 * j + ((w + (p >> 3)) & 3);
        const float* vc = Vh + (size_t)(m0 + 4 * mq) * PD + p;
        float4 mr = *(const float4*)&mk[m0 + 4 * mq];
        float4 v = make_float4(vc[0] * (mr.x * vscl), vc[PD] * (mr.y * vscl),
                               vc[2 * PD] * (mr.z * vscl), vc[3 * PD] * (mr.w * vscl));
        *(uint2*)&gVt[(p * 64 + 4 * mq) ^ ((p & 7) << 3)] = cvt4h(v);
    }
}

// ---------------- main: gload_lds staging + swapped-MFMA compute ----------------
__global__ __launch_bounds__(256, 4) void kde_main(
    const float* __restrict__ Qg, const float* __restrict__ maskg,
    const unsigned char* __restrict__ ws, float* __restrict__ Xg)
{
    __shared__ __align__(16) unsigned short sT[12288];  // Khi|Klo|Vt image (24576 B)
    __shared__ __align__(16) float scbL[256];           // cb x4 replicas (1024 B)
    __shared__ float sdQ[64];

    unsigned short* const sKh = sT;
    unsigned short* const sKl = sT + 4096;
    unsigned short* const sVt = sT + 8192;
    unsigned short* const sQh = sT;          // prologue reuse
    unsigned short* const sQl = sT + 4096;   // prologue reuse

    const int t    = threadIdx.x;
    const int lane = t & 63;
    const int w    = t >> 6;
    const int h    = lane >> 5;
    const int c    = lane & 31;
    const int wm   = w >> 1;
    const int wq   = w & 1;

    const int s   = blockIdx.x;
    const int xcd = s & 7;
    const int ii  = s >> 3;
    const int bh  = 6 * xcd + (ii >> 5);
    const int n0  = (ii & 31) * 64;
    const int b   = bh / NH;

    const float DN = 0.42044820762685725f;

    const float* Qh = Qg + (size_t)bh * NS * PD;
    const float* mk = maskg + (size_t)b * NS;
    const unsigned char* chb = ws + (size_t)bh * 32 * CHUNK;

    // ---- stage Q (scaled, split, swizzled) + diag_Q ----
    #pragma unroll
    for (int j = 0; j < 4; ++j) {
        const int idx = j * 256 + t;
        const int row = idx >> 4;
        const int u   = idx & 15;
        const float qs = mk[n0 + row] * DN;
        float4 v = *(const float4*)(Qh + (size_t)(n0 + row) * PD + 4 * u);
        v.x *= qs; v.y *= qs; v.z *= qs; v.w *= qs;
        uint2 h4, l4; split4(v, h4, l4);
        const int iu = (row * 64 + 4 * u) ^ ((row & 7) << 3);
        *(uint2*)&sQh[iu] = h4;
        *(uint2*)&sQl[iu] = l4;
        float d = dot4(v);
        d += __shfl_xor(d, 1); d += __shfl_xor(d, 2);
        d += __shfl_xor(d, 4); d += __shfl_xor(d, 8);
        if (u == 0) sdQ[row] = 0.5f * d;
    }
    __syncthreads();

    // ---- hoist Q B-fragments + per-lane dq ----
    s16x8 qbh[4], qbl[4];
    #pragma unroll
    for (int ks = 0; ks < 4; ++ks) {
        const int kc = 16 * ks + 8 * h;
        qbh[ks] = ldfrag(sQh, 32 * wq + c, kc);
        qbl[ks] = ldfrag(sQl, 32 * wq + c, kc);
    }
    const float dq = sdQ[32 * wq + c];
    __syncthreads();   // sT free for chunk staging

    f32x16 xacc[2];
    #pragma unroll
    for (int pt = 0; pt < 2; ++pt)
        #pragma unroll
        for (int r = 0; r < 16; ++r) xacc[pt][r] = 0.f;

    for (int mt = 0; mt < NS / 64; ++mt) {
        const unsigned char* chp = chb + (size_t)mt * CHUNK;

        // ---- stage chunk (24 KB + 1 KB) via global_load_lds ----
        #pragma unroll
        for (int j = 0; j < 6; ++j) {
            const int seg = 6 * w + j;
            gld16(chp + seg * 1024 + 16 * lane, (unsigned char*)sT + seg * 1024);
        }
        if (w == 0)
            gld16(chp + 24576 + 16 * lane, (unsigned char*)scbL);
        __syncthreads();

        // ---- S^T = Ks . Qs^T ----
        f32x16 acc;
        #pragma unroll
        for (int r = 0; r < 16; ++r) acc[r] = 0.f;

        __builtin_amdgcn_s_setprio(1);
        #pragma unroll
        for (int ks = 0; ks < 4; ++ks) {
            const int kc = 16 * ks + 8 * h;
            const s16x8 kh = ldfrag(sKh, 32 * wm + c, kc);
            const s16x8 kl = ldfrag(sKl, 32 * wm + c, kc);
            acc = MFMA32(kh, qbh[ks], acc);
            acc = MFMA32(kh, qbl[ks], acc);
            acc = MFMA32(kl, qbh[ks], acc);
        }
        __builtin_amdgcn_s_setprio(0);

        // ---- P = exp(S - dq + cb) in-register ----
        float pv[16];
        #pragma unroll
        for (int g = 0; g < 4; ++g) {
            const f32x4 cb4 = *(const f32x4*)&scbL[32 * wm + 8 * g + 4 * h];
            #pragma unroll
            for (int e = 0; e < 4; ++e)
                pv[4 * g + e] = __expf(acc[4 * g + e] - dq + cb4[e]);
        }

        // ---- X_partial += P^T . Vs ----
        #pragma unroll
        for (int ks2 = 0; ks2 < 2; ++ks2) {
            const int bb = 8 * ks2;
            unsigned w0 = pk2(pv[bb + 0], pv[bb + 1]);
            unsigned w1 = pk2(pv[bb + 2], pv[bb + 3]);
            unsigned w2 = pk2(pv[bb + 4], pv[bb + 5]);
            unsigned w3 = pk2(pv[bb + 6], pv[bb + 7]);
            pswap(w0, w2);
            pswap(w1, w3);
            union { unsigned int u[4]; s16x8 v; } pa;
            pa.u[0] = w0; pa.u[1] = w1; pa.u[2] = w2; pa.u[3] = w3;
            const int kc = 32 * wm + 16 * ks2 + 8 * h;
            __builtin_amdgcn_s_setprio(1);
            #pragma unroll
            for (int pt = 0; pt < 2; ++pt) {
                const s16x8 vb = ldfrag(sVt, 32 * pt + c, kc);
                xacc[pt] = MFMA32(pa.v, vb, xacc[pt]);
            }
            __builtin_amdgcn_s_setprio(0);
        }
        __syncthreads();   // protect sT before next staging
    }

    // ---- cross-wave (wm) reduction via LDS, then write X ----
    float* sX = (float*)sT;
    if (wm == 0) {
        #pragma unroll
        for (int pt = 0; pt < 2; ++pt)
            #pragma unroll
            for (int r = 0; r < 16; ++r) {
                const int row = 32 * wq + (r & 3) + 8 * (r >> 2) + 4 * h;
                sX[row * 64 + 32 * pt + c] = xacc[pt][r];
            }
    }
    __syncthreads();
    if (wm == 1) {
        float* Xh = Xg + (size_t)bh * NS * PD;
        #pragma unroll
        for (int pt = 0; pt < 2; ++pt)
            #pragma unroll
            for (int r = 0; r < 16; ++r) {
                const int row = 32 * wq + (r & 3) + 8 * (r >> 2) + 4 * h;
                const int col = 32 * pt + c;
                Xh[(size_t)(n0 + row) * PD + col] = sX[row * 64 + col] + xacc[pt][r];
            }
    }
}

// ---------------- fallback (exact R6 kernel) if ws too small ----------------
__global__ __launch_bounds__(256, 2) void kde_attn_fb(
    const float* __restrict__ Qg, const float* __restrict__ Kg,
    const float* __restrict__ Vg, const float* __restrict__ maskg,
    float* __restrict__ Xg)
{
    __shared__ __align__(16) unsigned short sKh[4096], sKl[4096], sVt[4096];
    __shared__ __align__(16) unsigned short sU[8192];
    __shared__ __align__(16) float scb[64];
    __shared__ float sdQ[64], red[4];

    unsigned short* const sQh = sU;
    unsigned short* const sQl = sU + 4096;

    const int t    = threadIdx.x;
    const int lane = t & 63;
    const int w    = t >> 6;
    const int h    = lane >> 5;
    const int c    = lane & 31;
    const int wm   = w >> 1;
    const int wq   = w & 1;

    const int s   = blockIdx.x;
    const int xcd = s & 7;
    const int ii  = s >> 3;
    const int bh  = 6 * xcd + (ii >> 5);
    const int n0  = (ii & 31) * 64;
    const int b   = bh / NH;

    const float DN = 0.42044820762685725f;

    const float* Qh = Qg + (size_t)bh * NS * PD;
    const float* Kh = Kg + (size_t)bh * NS * PD;
    const float* Vh = Vg + (size_t)bh * NS * PD;
    const float* mk = maskg + (size_t)b * NS;

    {
        float sm = 0.f;
        for (int i = t; i < NS; i += 256) sm += mk[i];
        #pragma unroll
        for (int m = 1; m < 64; m <<= 1) sm += __shfl_xor(sm, m);
        if (lane == 0) red[w] = sm;
    }

    #pragma unroll
    for (int j = 0; j < 4; ++j) {
        const int idx = j * 256 + t;
        const int row = idx >> 4;
        const int u   = idx & 15;
        const float qs = mk[n0 + row] * DN;
        float4 v = *(const float4*)(Qh + (size_t)(n0 + row) * PD + 4 * u);
        v.x *= qs; v.y *= qs; v.z *= qs; v.w *= qs;
        uint2 h4, l4; split4(v, h4, l4);
        const int iu = (row * 64 + 4 * u) ^ ((row & 7) << 3);
        *(uint2*)&sQh[iu] = h4;
        *(uint2*)&sQl[iu] = l4;
        float d = dot4(v);
        d += __shfl_xor(d, 1); d += __shfl_xor(d, 2);
        d += __shfl_xor(d, 4); d += __shfl_xor(d, 8);
        if (u == 0) sdQ[row] = 0.5f * d;
    }
    __syncthreads();

    const float npn  = red[0] + red[1] + red[2] + red[3];
    const float vscl = DN / npn;

    s16x8 qbh[4], qbl[4];
    #pragma unroll
    for (int ks = 0; ks < 4; ++ks) {
        const int kc = 16 * ks + 8 * h;
        qbh[ks] = ldfrag(sQh, 32 * wq + c, kc);
        qbl[ks] = ldfrag(sQl, 32 * wq + c, kc);
    }
    const float dq = sdQ[32 * wq + c];

    f32x16 xacc[2];
    #pragma unroll
    for (int pt = 0; pt < 2; ++pt)
        #pragma unroll
        for (int r = 0; r < 16; ++r) xacc[pt][r] = 0.f;

    for (int mt = 0; mt < NS / 64; ++mt) {
        const int m0 = mt * 64;

        #pragma unroll
        for (int j = 0; j < 4; ++j) {
            const int idx = j * 256 + t;
            const int row = idx >> 4;
            const int u   = idx & 15;
            const float mr  = mk[m0 + row];
            const float ksc = mr * DN;
            float4 v = *(const float4*)(Kh + (size_t)(m0 + row) * PD + 4 * u);
            v.x *= ksc; v.y *= ksc; v.z *= ksc; v.w *= ksc;
            uint2 h4, l4; split4(v, h4, l4);
            const int iu = (row * 64 + 4 * u) ^ ((row & 7) << 3);
            *(uint2*)&sKh[iu] = h4;
            *(uint2*)&sKl[iu] = l4;
            float d = dot4(v);
            d += __shfl_xor(d, 1); d += __shfl_xor(d, 2);
            d += __shfl_xor(d, 4); d += __shfl_xor(d, 8);
            if (u == 0) scb[row] = fmaf(-1.0e9f, 1.f - mr, -0.5f * d);
        }
        #pragma unroll
        for (int j = 0; j < 4; ++j) {
            const int p  = lane;
            const int mq = 4 * j + ((w + (p >> 3)) & 3);
            const float* vc = Vh + (size_t)(m0 + 4 * mq) * PD + p;
            float4 mr = *(const float4*)&mk[m0 + 4 * mq];
            float4 v = make_float4(vc[0] * (mr.x * vscl), vc[PD] * (mr.y * vscl),
                                   vc[2 * PD] * (mr.z * vscl), vc[3 * PD] * (mr.w * vscl));
            *(uint2*)&sVt[(p * 64 + 4 * mq) ^ ((p & 7) << 3)] = cvt4h(v);
        }
        __syncthreads();

        f32x16 acc;
        #pragma unroll
        for (int r = 0; r < 16; ++r) acc[r] = 0.f;

        __builtin_amdgcn_s_setprio(1);
        #pragma unroll
        for (int ks = 0; ks < 4; ++ks) {
            const int kc = 16 * ks + 8 * h;
            const s16x8 kh = ldfrag(sKh, 32 * wm + c, kc);
            const s16x8 kl = ldfrag(sKl, 32 * wm + c, kc);
            acc = MFMA32(kh, qbh[ks], acc);
            acc = MFMA32(kh, qbl[ks], acc);
            acc = MFMA32(kl, qbh[ks], acc);
        }
        __builtin_amdgcn_s_setprio(0);

        float pv[16];
        #pragma unroll
        for (int g = 0; g < 4; ++g) {
            const f32x4 cb4 = *(const f32x4*)&scb[32 * wm + 8 * g + 4 * h];
            #pragma unroll
            for (int e = 0; e < 4; ++e)
                pv[4 * g + e] = __expf(acc[4 * g + e] - dq + cb4[e]);
        }

        #pragma unroll
        for (int ks2 = 0; ks2 < 2; ++ks2) {
            const int bb = 8 * ks2;
            unsigned w0 = pk2(pv[bb + 0], pv[bb + 1]);
            unsigned w1 = pk2(pv[bb + 2], pv[bb + 3]);
            unsigned w2 = pk2(pv[bb + 4], pv[bb + 5]);
            unsigned w3 = pk2(pv[bb + 6], pv[bb + 7]);
            pswap(w0, w2);
            pswap(w1, w3);
            union { unsigned int u[4]; s16x8 v; } pa;
            pa.u[0] = w0; pa.u[1] = w1; pa.u[2] = w2; pa.u[3] = w3;
            const int kc = 32 * wm + 16 * ks2 + 8 * h;
            __builtin_amdgcn_s_setprio(1);
            #pragma unroll
            for (int pt = 0; pt < 2; ++pt) {
                const s16x8 vb = ldfrag(sVt, 32 * pt + c, kc);
                xacc[pt] = MFMA32(pa.v, vb, xacc[pt]);
            }
            __builtin_amdgcn_s_setprio(0);
        }
        __syncthreads();
    }

    float* sX = (float*)sU;
    if (wm == 0) {
        #pragma unroll
        for (int pt = 0; pt < 2; ++pt)
            #pragma unroll
            for (int r = 0; r < 16; ++r) {
                const int row = 32 * wq + (r & 3) + 8 * (r >> 2) + 4 * h;
                sX[row * 64 + 32 * pt + c] = xacc[pt][r];
            }
    }
    __syncthreads();
    if (wm == 1) {
        float* Xh = Xg + (size_t)bh * NS * PD;
        #pragma unroll
        for (int pt = 0; pt < 2; ++pt)
            #pragma unroll
            for (int r = 0; r < 16; ++r) {
                const int row = 32 * wq + (r & 3) + 8 * (r >> 2) + 4 * h;
                const int col = 32 * pt + c;
                Xh[(size_t)(n0 + row) * PD + col] = sX[row * 64 + col] + xacc[pt][r];
            }
    }
}

extern "C" void kernel_launch(void* const* d_in, const int* in_sizes, int n_in,
                              void* d_out, int out_size, void* d_ws, size_t ws_size,
                              hipStream_t stream) {
    const float* Q    = (const float*)d_in[0];
    const float* K    = (const float*)d_in[1];
    const float* V    = (const float*)d_in[2];
    const float* mask = (const float*)d_in[3];
    float* X = (float*)d_out;

    const size_t need = (size_t)NB * NH * 32 * CHUNK;   // 39.3 MB
    if (d_ws != nullptr && ws_size >= need) {
        kde_pre<<<dim3(NB * NH * 32), dim3(256), 0, stream>>>(K, V, mask, (unsigned char*)d_ws);
        kde_main<<<dim3(NB * NH * 32), dim3(256), 0, stream>>>(Q, mask, (const unsigned char*)d_ws, X);
    } else {
        kde_attn_fb<<<dim3(NB * NH * 32), dim3(256), 0, stream>>>(Q, K, V, mask, X);
    }
}